// Round 16
// baseline (135.446 us; speedup 1.0000x reference)
//
#include <hip/hip_runtime.h>

// SoftAttentionAlignment B=8, L=2048, D=128 fp32. MFMA flash attention, both dirs.
// R21 = R11/R20 dataflow with ASYNC DMA STAGING (global_load_lds width=16):
//   - staging no longer transits VGPRs: 8 DMA instrs/wave/tile replace
//     8 global_load + 8 ds_write_b128 (+ their vmcnt serialization + 24 VGPRs).
//   - K LDS: unpadded [32][128] f16 (contiguous 1KB windows, DMA-compatible) with
//     XOR swizzle off^=((j&7)<<4) applied on the GLOBAL SOURCE per-lane address
//     (DMA dest must stay linear; rule #21 both-sides involution) and identically
//     on fragment reads -> read start-banks uniform over 8 slots, conflict-free
//     (replaces the 136-pad workaround for the mod-128 8-way collapse).
//   - V LDS: [128][32] bf16 is already linear per 1KB window -> DMA unswizzled;
//     read pattern unchanged (conflict-free).
//   - double-buffered (64KB/block, 2 blocks/CU = 131.6KB), ONE barrier per tile,
//     explicit s_waitcnt vmcnt(0) before it (t+1 DMA landed; buf^1 reads done).
//   - XCD swizzle retained (R20: FETCH 77->20.5MB, time-neutral, harmless).
// Evidence: R20 plateau 62us with NOTHING saturated; LDS pipe + staging
// instruction stream ~50-60% = highest demand. This is the one untried
// guide-tier lever (Common-mistake #1; GEMM ladder +67% from this alone).

typedef __bf16    bf16;
typedef _Float16  f16;
typedef __bf16    bf16x4 __attribute__((ext_vector_type(4)));
typedef _Float16  f16x4  __attribute__((ext_vector_type(4)));
typedef __bf16    bf16x8 __attribute__((ext_vector_type(8)));
typedef _Float16  f16x8  __attribute__((ext_vector_type(8)));
typedef float     floatx4 __attribute__((ext_vector_type(4)));
typedef unsigned int uintx4 __attribute__((ext_vector_type(4)));

#define NB 8
#define SL 2048
#define TI 64
#define NT 32            // 32 j-tiles of 32 per group (group owns 1024 j)

#define F16SZ (NB * SL * 128 * 2)   // 4,194,304 B per converted array

// LDS map per block: group g at g*32768: K0 8KB | V0 8KB | K1 8KB | V1 8KB.
// aOut fp32 [64][132] = 33792 B overlaps buffers (post-loop); sL at 65536.
#define GSPAN    32768
#define OFF_L    65536
#define LDS_BYTES 65792

__device__ __forceinline__ void gl2lds16(const void* g, void* l) {
    __builtin_amdgcn_global_load_lds(
        (const __attribute__((address_space(1))) unsigned int*)g,
        (__attribute__((address_space(3))) unsigned int*)(unsigned)(uintptr_t)l,
        16, 0, 0);
}

// ---------------- prepass: fp32 -> f16 (same layout) + bf16 transposed ----------
__global__ __launch_bounds__(256)
void prepass_cvt(const float* __restrict__ x1, const float* __restrict__ x2,
                 char* __restrict__ ws)
{
    __shared__ float tile[64 * 129];
    const int tid = threadIdx.x;
    const int j0  = blockIdx.x * 64;
    const int b   = blockIdx.y;
    const int z   = blockIdx.z;
    const float* src = z ? x2 : x1;
    f16*  oF = (f16*) (ws + (size_t)z * F16SZ);
    bf16* oT = (bf16*)(ws + 2 * (size_t)F16SZ + (size_t)z * F16SZ);

    #pragma unroll
    for (int n = 0; n < 8; ++n) {
        int ci = n * 256 + tid;              // 0..2047
        int row = ci >> 5, c4 = ci & 31;
        const float4 v = *(const float4*)(src + ((size_t)b * SL + j0 + row) * 128 + c4 * 4);
        tile[row * 129 + c4 * 4 + 0] = v.x;
        tile[row * 129 + c4 * 4 + 1] = v.y;
        tile[row * 129 + c4 * 4 + 2] = v.z;
        tile[row * 129 + c4 * 4 + 3] = v.w;
        f16x4 h; h[0] = (f16)v.x; h[1] = (f16)v.y; h[2] = (f16)v.z; h[3] = (f16)v.w;
        *(f16x4*)(oF + ((size_t)b * SL + j0 + row) * 128 + c4 * 4) = h;
    }
    __syncthreads();
    #pragma unroll
    for (int n = 0; n < 8; ++n) {
        int fi = n * 256 + tid;              // 0..2047
        int jg = fi & 15, d = fi >> 4;
        bf16x4 o;
        #pragma unroll
        for (int i = 0; i < 4; ++i) o[i] = (bf16)tile[(jg * 4 + i) * 129 + d];
        *(bf16x4*)(oT + ((size_t)b * 128 + d) * SL + j0 + jg * 4) = o;
    }
}

// ---------------- main kernel -----------------------------------------------
// STAGE tile TT into (KN, VN): 8 x global_load_lds per wave (4 K + 4 V).
// K windows: (h*4+n)*1024B; lane i -> j = h*16+n*4+(i>>4), src col swizzled.
// V windows: (h*4+n)*1024B; lane i -> d = (h*4+n)*16+(i>>2), chunk i&3.
#define STAGE(TT, KN, VN)                                                          \
    {                                                                              \
        const char* kt = kgb + (size_t)(TT) * 8192;                                \
        const char* vt = vgb + (size_t)(TT) * 64;                                  \
        _Pragma("unroll")                                                          \
        for (int n = 0; n < 4; ++n) {                                              \
            int jj = h * 16 + n * 4 + (lane >> 4);                                 \
            int ko = jj * 256 + (((lane & 15) << 4) ^ ((4 * (n & 1) + (lane >> 4)) << 4)); \
            int dd = (h * 4 + n) * 16 + (lane >> 2);                               \
            int vo = dd * 4096 + (lane & 3) * 16;                                  \
            gl2lds16(kt + ko, (char*)(KN) + (h * 4 + n) * 1024);                   \
            gl2lds16(vt + vo, (char*)(VN) + (h * 4 + n) * 1024);                   \
        }                                                                          \
    }

#define COMPUTE(KC, VC)                                                            \
    {                                                                              \
        floatx4 Sf[2][2];                                                          \
        Sf[0][0] = (floatx4){0.f,0.f,0.f,0.f}; Sf[0][1] = (floatx4){0.f,0.f,0.f,0.f}; \
        Sf[1][0] = (floatx4){0.f,0.f,0.f,0.f}; Sf[1][1] = (floatx4){0.f,0.f,0.f,0.f}; \
        __builtin_amdgcn_s_setprio(1);                                             \
        _Pragma("unroll")                                                          \
        for (int kk = 0; kk < 4; ++kk) {                                           \
            const int koff = (kk * 64 + lq16) ^ x16;                               \
            f16x8 aK0 = *(const f16x8*)((const char*)(KC) + lr * 256 + koff);      \
            f16x8 aK1 = *(const f16x8*)((const char*)(KC) + (16 + lr) * 256 + koff); \
            Sf[0][0] = __builtin_amdgcn_mfma_f32_16x16x32_f16(aK0, aQ[0][kk], Sf[0][0], 0, 0, 0); \
            Sf[0][1] = __builtin_amdgcn_mfma_f32_16x16x32_f16(aK1, aQ[0][kk], Sf[0][1], 0, 0, 0); \
            Sf[1][0] = __builtin_amdgcn_mfma_f32_16x16x32_f16(aK0, aQ[1][kk], Sf[1][0], 0, 0, 0); \
            Sf[1][1] = __builtin_amdgcn_mfma_f32_16x16x32_f16(aK1, aQ[1][kk], Sf[1][1], 0, 0, 0); \
        }                                                                          \
        __builtin_amdgcn_s_setprio(0);                                             \
        bf16x8 aP[2];                                                              \
        _Pragma("unroll")                                                          \
        for (int rb = 0; rb < 2; ++rb) {                                           \
            float p00 = __expf(Sf[rb][0][0]), p01 = __expf(Sf[rb][0][1]);          \
            float p02 = __expf(Sf[rb][0][2]), p03 = __expf(Sf[rb][0][3]);          \
            float p10 = __expf(Sf[rb][1][0]), p11 = __expf(Sf[rb][1][1]);          \
            float p12 = __expf(Sf[rb][1][2]), p13 = __expf(Sf[rb][1][3]);          \
            l_acc[rb] += ((p00 + p01) + (p02 + p03)) + ((p10 + p11) + (p12 + p13)); \
            unsigned int A0, B0, A1, B1;                                           \
            asm("v_cvt_pk_bf16_f32 %0, %1, %2" : "=v"(A0) : "v"(p00), "v"(p01));   \
            asm("v_cvt_pk_bf16_f32 %0, %1, %2" : "=v"(B0) : "v"(p02), "v"(p03));   \
            asm("v_cvt_pk_bf16_f32 %0, %1, %2" : "=v"(A1) : "v"(p10), "v"(p11));   \
            asm("v_cvt_pk_bf16_f32 %0, %1, %2" : "=v"(B1) : "v"(p12), "v"(p13));   \
            asm("v_permlane32_swap_b32 %0, %1" : "+v"(A0), "+v"(A1));              \
            asm("v_permlane16_swap_b32 %0, %1" : "+v"(A0), "+v"(A1));              \
            asm("v_permlane32_swap_b32 %0, %1" : "+v"(B0), "+v"(B1));              \
            asm("v_permlane16_swap_b32 %0, %1" : "+v"(B0), "+v"(B1));              \
            uintx4 fr; fr.x = A0; fr.y = B0; fr.z = A1; fr.w = B1;                 \
            aP[rb] = __builtin_bit_cast(bf16x8, fr);                               \
        }                                                                          \
        __builtin_amdgcn_s_setprio(1);                                             \
        _Pragma("unroll")                                                          \
        for (int nd = 0; nd < 8; ++nd) {                                           \
            bf16x8 bV = *(const bf16x8*)((const char*)(VC) + (nd * 16 + lr) * 64 + lq16); \
            Oacc[0][nd] = __builtin_amdgcn_mfma_f32_16x16x32_bf16(aP[0], bV, Oacc[0][nd], 0, 0, 0); \
            Oacc[1][nd] = __builtin_amdgcn_mfma_f32_16x16x32_bf16(aP[1], bV, Oacc[1][nd], 0, 0, 0); \
        }                                                                          \
        __builtin_amdgcn_s_setprio(0);                                             \
    }

#define TILE_BODY(T, KC, VC, KN, VN)                                               \
    {                                                                              \
        if ((T) + 1 < NT) { STAGE((T) + 1, KN, VN) }                               \
        COMPUTE(KC, VC)                                                            \
        asm volatile("s_waitcnt vmcnt(0)" ::: "memory");                           \
        __syncthreads();                                                           \
    }

__global__ __launch_bounds__(256, 2)
void soft_attn_align_mfma(const float* __restrict__ x1,
                          const float* __restrict__ x2,
                          const char* __restrict__ ws,
                          float* __restrict__ out)
{
    __shared__ __align__(16) char lds_raw[LDS_BYTES];

    const int tid  = threadIdx.x;
    const int lane = tid & 63;
    const int wv   = tid >> 6;          // 0..3
    const int g    = wv >> 1;           // j-half group
    const int rowbase = (wv & 1) * 32;  // wave's 32 q-rows (two 16-row blocks)
    const int lr   = lane & 15;
    const int lq   = lane >> 4;
    const int t128 = tid & 127;         // thread id within group
    const int h    = t128 >> 6;         // wave index within group (0/1)
    const int lq16 = lq * 16;
    const int x16  = (lr & 7) << 4;     // K read-side XOR swizzle

    char* gb  = lds_raw + g * GSPAN;
    char* K0p = gb;
    char* V0p = gb + 8192;
    char* K1p = gb + 16384;
    char* V1p = gb + 24576;
    float* aOut = (float*)(lds_raw);     // [64][132] fp32 (epilogue/combine)
    float* sL   = (float*)(lds_raw + OFF_L);

    // bijective XCD swizzle for 512 wgs (verified R17/R20): swz = dir*256+bi*32+ix
    const int lid = blockIdx.x + 32 * (blockIdx.y + 8 * blockIdx.z);  // 0..511
    const int swz = (lid & 7) * 64 + (lid >> 3);                      // 0..511
    const int ix  = swz & 31;
    const int bi  = (swz >> 5) & 7;
    const int dir = swz >> 8;
    const int i0  = ix * TI;

    const float* xq = dir ? x2 : x1;                     // epilogue (exact fp32)
    const f16*  x1f = (const f16*)(ws);
    const f16*  x2f = (const f16*)(ws + F16SZ);
    const bf16* x1T = (const bf16*)(ws + 2 * (size_t)F16SZ);
    const bf16* x2T = (const bf16*)(ws + 3 * (size_t)F16SZ);
    const f16*  xqf  = dir ? x2f : x1f;
    const f16*  xkvf = dir ? x1f : x2f;
    const bf16* xvT  = dir ? x1T : x2T;

    // group-base byte pointers for DMA staging
    const char* kgb = (const char*)(xkvf + ((size_t)bi * SL + g * 1024) * 128);
    const char* vgb = (const char*)(xvT + (size_t)bi * 128 * SL + g * 1024);

    // ---- Q fragments (f16) straight from converted array ----
    f16x8 aQ[2][4];
    #pragma unroll
    for (int rb = 0; rb < 2; ++rb) {
        const f16* qrow = xqf + ((size_t)bi * SL + i0 + rowbase + rb * 16 + lr) * 128;
        #pragma unroll
        for (int kk = 0; kk < 4; ++kk)
            aQ[rb][kk] = *(const f16x8*)(qrow + kk * 32 + lq * 8);
    }

    float   l_acc[2] = {0.f, 0.f};
    floatx4 Oacc[2][8];
    #pragma unroll
    for (int rb = 0; rb < 2; ++rb)
        #pragma unroll
        for (int nd = 0; nd < 8; ++nd) Oacc[rb][nd] = (floatx4){0.f, 0.f, 0.f, 0.f};

    // ---- prologue: DMA tile 0 into buf0 ----
    STAGE(0, K0p, V0p)
    asm volatile("s_waitcnt vmcnt(0)" ::: "memory");
    __syncthreads();

    for (int t = 0; t < NT; t += 2) {
        TILE_BODY(t,     K0p, V0p, K1p, V1p)
        TILE_BODY(t + 1, K1p, V1p, K0p, V0p)
    }

    // ---- row sums: lane holds partial for i = rowbase+16rb+lr; reduce over lq ----
    float l_row[2][4];
    #pragma unroll
    for (int rb = 0; rb < 2; ++rb) {
        float lv = l_acc[rb];
        lv += __shfl_xor(lv, 16, 64);
        lv += __shfl_xor(lv, 32, 64);
        #pragma unroll
        for (int r = 0; r < 4; ++r)
            l_row[rb][r] = __shfl(lv, lq * 4 + r, 64);
    }

    // (loop ended with a barrier; safe to overwrite LDS with aOut now)

    // ---- combine j-halves: group 1 publishes partials, group 0 merges ----
    if (g == 1) {
        #pragma unroll
        for (int rb = 0; rb < 2; ++rb)
            #pragma unroll
            for (int r = 0; r < 4; ++r) {
                int row = rowbase + rb * 16 + lq * 4 + r;
                #pragma unroll
                for (int nd = 0; nd < 8; ++nd)
                    aOut[row * 132 + nd * 16 + lr] = Oacc[rb][nd][r];
                if (lr == 0) sL[row] = l_row[rb][r];
            }
    }
    __syncthreads();
    if (g == 0) {
        #pragma unroll
        for (int rb = 0; rb < 2; ++rb)
            #pragma unroll
            for (int r = 0; r < 4; ++r) {
                int row = rowbase + rb * 16 + lq * 4 + r;
                float inv = 1.0f / (l_row[rb][r] + sL[row]);
                #pragma unroll
                for (int nd = 0; nd < 8; ++nd) {
                    int idx = row * 132 + nd * 16 + lr;
                    aOut[idx] = (Oacc[rb][nd][r] + aOut[idx]) * inv;
                }
            }
    }
    __syncthreads();

    // ---- epilogue: out row = [q, A, q-A, q*A], q exact fp32 from global ----
    float* outb = out + ((size_t)dir * NB * SL + (size_t)bi * SL + i0) * 512;
    #pragma unroll
    for (int k = 0; k < 8; ++k) {
        int s = tid + 256 * k;          // 2048 slots: row (0..63), c4 (0..31)
        int r = s >> 5, c4 = s & 31;
        float4 a = *(const float4*)(aOut + r * 132 + c4 * 4);
        float4 q = *(const float4*)(xq + ((size_t)bi * SL + i0 + r) * 128 + c4 * 4);
        float4 d, m;
        d.x = q.x - a.x; d.y = q.y - a.y; d.z = q.z - a.z; d.w = q.w - a.w;
        m.x = q.x * a.x; m.y = q.y * a.y; m.z = q.z * a.z; m.w = q.w * a.w;
        float4* orow = (float4*)(outb + (size_t)r * 512);
        orow[c4]      = q;
        orow[32 + c4] = a;
        orow[64 + c4] = d;
        orow[96 + c4] = m;
    }
}

extern "C" void kernel_launch(void* const* d_in, const int* in_sizes, int n_in,
                              void* d_out, int out_size, void* d_ws, size_t ws_size,
                              hipStream_t stream) {
    const float* x1 = (const float*)d_in[0];
    const float* x2 = (const float*)d_in[1];
    float* out = (float*)d_out;
    (void)in_sizes; (void)n_in; (void)out_size; (void)ws_size;

    dim3 pgrid(SL / 64, NB, 2);
    prepass_cvt<<<pgrid, dim3(256), 0, stream>>>(x1, x2, (char*)d_ws);

    dim3 grid(SL / TI, NB, 2);
    soft_attn_align_mfma<<<grid, dim3(256), 0, stream>>>(x1, x2, (const char*)d_ws, out);
}